// Round 1
// baseline (248.065 us; speedup 1.0000x reference)
//
#include <hip/hip_runtime.h>

// out[l, o*128+i, n, m] = sum_{j,kw} X(m+kw-1) * W[j,kw,i]
//   X(m') = 0 if m'<0 or m'>=28 else x[l, o*128+j, n1, (m'-1)%28],  n1=(n-1)%28
// LDS xsp[r][j] holds X(r-1): r=0 and r>=29 are zero pad; staging puts
// x[...,n1,mm] at r = 1 + (mm+1)%28. A_kw[m][j] = xsp[m+kw][j].

typedef __bf16  bf16x8 __attribute__((ext_vector_type(8)));
typedef float  f32x16 __attribute__((ext_vector_type(16)));

__global__ __launch_bounds__(256, 2)
void shiftconv_kernel(const float* __restrict__ x,
                      const float* __restrict__ Wm,
                      float* __restrict__ out)
{
    __shared__ unsigned short xsp[34 * 128];  // bf16 bits, swizzled

    const int tid  = threadIdx.x;
    const int wave = tid >> 6;
    const int lane = tid & 63;
    const int lo   = lane & 31;
    const int hi   = lane >> 5;

    const int b  = blockIdx.x;        // 1024 blocks
    const int l  = b >> 3;            // 0..127
    const int o  = (b >> 2) & 1;      // 0..1
    const int nc = b & 3;             // 0..3 (7 h-rows each)

    // ---- W fragments in registers: bw[kw][jc], B[jl][i] = W[j0+jl][kw][i] ----
    bf16x8 bw[3][8];
    {
        const int i = wave * 32 + lo;
#pragma unroll
        for (int kw = 0; kw < 3; ++kw) {
#pragma unroll
            for (int jc = 0; jc < 8; ++jc) {
                const int j0 = jc * 16 + hi * 8;
#pragma unroll
                for (int e = 0; e < 8; ++e) {
                    bw[kw][jc][e] = (__bf16)Wm[(((j0 + e) * 3) + kw) * 128 + i];
                }
            }
        }
    }

    // ---- zero pad rows {0, 29..33} (once; rows 1..28 rewritten every n1) ----
    {
        const int rl[6] = {0, 29, 30, 31, 32, 33};
#pragma unroll
        for (int q = 0; q < 3; ++q) {
            const int e  = q * 256 + tid;   // 0..767
            const int rr = rl[e >> 7];
            const int j  = e & 127;
            xsp[rr * 128 + (j ^ ((rr & 7) << 3))] = 0;
        }
    }

    const float* xbase = x   + (size_t)(l * 256 + o * 128) * 784;
    float*       obase = out + (size_t)(l * 256 + o * 128) * 784;

    for (int n1 = nc * 7; n1 < nc * 7 + 7; ++n1) {
        __syncthreads();  // pad-zero / previous compute done before restaging

        // ---- stage x[l,o,:,n1,:] -> xsp (bf16, swizzled) ----
        for (int g = tid; g < 896; g += 256) {       // 128 j * 7 float4
            const int j  = g / 7;
            const int mq = g - j * 7;
            const float4 v = *reinterpret_cast<const float4*>(
                xbase + j * 784 + n1 * 28 + mq * 4);
            const float vv[4] = {v.x, v.y, v.z, v.w};
#pragma unroll
            for (int e = 0; e < 4; ++e) {
                const int m = mq * 4 + e;
                const int r = (m == 27) ? 1 : (m + 2);
                union { __bf16 h; unsigned short u; } cv;
                cv.h = (__bf16)vv[e];
                xsp[r * 128 + (j ^ ((r & 7) << 3))] = cv.u;
            }
        }
        __syncthreads();

        // ---- 24 MFMA: acc[m][i] over m=0..31 (>=28 zero), i = wave*32+lo ----
        f32x16 acc = {0,0,0,0, 0,0,0,0, 0,0,0,0, 0,0,0,0};
#pragma unroll
        for (int kw = 0; kw < 3; ++kw) {
#pragma unroll
            for (int jc = 0; jc < 8; ++jc) {
                const int row = kw + lo;                 // A row = lane&31
                const int j0  = jc * 16 + hi * 8;        // A k  = 8*(lane>>5)+e
                const bf16x8 a = *reinterpret_cast<const bf16x8*>(
                    &xsp[row * 128 + (j0 ^ ((row & 7) << 3))]);
                acc = __builtin_amdgcn_mfma_f32_32x32x16_bf16(a, bw[kw][jc], acc, 0, 0, 0);
            }
        }

        // ---- store: reg r=4q+s -> m = 8q+4*hi+s ; col i = lane&31 ----
        const int n = (n1 + 1) % 28;
        const int i = wave * 32 + lo;
        float* op = obase + (size_t)i * 784 + n * 28;
#pragma unroll
        for (int q = 0; q < 4; ++q) {
            const int m0 = 8 * q + 4 * hi;
            if (m0 <= 24) {   // m0==28 (q=3,hi=1) is padding
                float4 st = make_float4(acc[4*q+0], acc[4*q+1], acc[4*q+2], acc[4*q+3]);
                *reinterpret_cast<float4*>(op + m0) = st;
            }
        }
    }
}

extern "C" void kernel_launch(void* const* d_in, const int* in_sizes, int n_in,
                              void* d_out, int out_size, void* d_ws, size_t ws_size,
                              hipStream_t stream) {
    const float* x  = (const float*)d_in[0];   // (128, 256, 28, 28) fp32
    const float* Wm = (const float*)d_in[1];   // (128, 3, 128) fp32
    float* out = (float*)d_out;                // (128, 256, 28, 28) fp32
    hipLaunchKernelGGL(shiftconv_kernel, dim3(1024), dim3(256), 0, stream, x, Wm, out);
}

// Round 2
// 222.652 us; speedup vs baseline: 1.1141x; 1.1141x over previous
//
#include <hip/hip_runtime.h>

// out[l, o*128+i, n, m] = sum_{j,kw} X(m+kw-1) * W[j,kw,i]
//   X(m') = 0 if m'<0 or m'>=28 else x[l, o*128+j, n1, (m'-1)%28],  n1=(n-1)%28
// LDS xsp[r][j] holds X(r-1): r=0,29 zero pad; staging puts x[...,n1,m] at
// r = 1+(m+1)%28. A_kw[m][j] = xsp[m+kw][j]. Double-buffered, 8-wave blocks,
// 16x16x32 MFMA (wave owns 16 i-cols, 2 M-tiles covering m=0..27(+pad)).

typedef __bf16 bf16x8 __attribute__((ext_vector_type(8)));
typedef float  f32x4  __attribute__((ext_vector_type(4)));

__device__ __forceinline__ int swz(int r, int j) {
    return r * 128 + (j ^ ((r & 7) << 3));
}

// e is a compile-time constant inside the unroll; (&V.x)[e] stays in regs.
#define STAGE_WRITE(BUF, V, J, MQ)                                   \
    {                                                                \
        _Pragma("unroll")                                            \
        for (int e = 0; e < 4; ++e) {                                \
            const int m = (MQ) * 4 + e;                              \
            const int r = (m == 27) ? 1 : (m + 2);                   \
            union { __bf16 h; unsigned short u; } cv;                \
            cv.h = (__bf16)((&(V).x)[e]);                            \
            xsp[BUF][swz(r, (J))] = cv.u;                            \
        }                                                            \
    }

__global__ __launch_bounds__(512, 4)
void shiftconv_kernel(const float* __restrict__ x,
                      const float* __restrict__ Wm,
                      float* __restrict__ out)
{
    __shared__ unsigned short xsp[2][34 * 128];

    const int tid  = threadIdx.x;
    const int wave = tid >> 6;     // 0..7
    const int lane = tid & 63;
    const int l15  = lane & 15;
    const int hi2  = lane >> 4;    // 0..3

    const int b  = blockIdx.x;     // 1024 blocks
    const int l  = b >> 3;
    const int o  = (b >> 2) & 1;
    const int nc = b & 3;          // 7 h-rows each

    const float* xbase = x   + (size_t)(l * 256 + o * 128) * 784;
    float*       obase = out + (size_t)(l * 256 + o * 128) * 784;

    // staging assignment: 896 float4 (128 j x 7 mq) over 512 threads
    const int ga  = tid;
    const int gb  = tid + 512;
    const int ja  = ga / 7,  ma = ga - ja * 7;
    const int jb2 = gb / 7,  mb = gb - jb2 * 7;
    const bool vb = (gb < 896);    // wave-uniform (waves 6,7 idle on 2nd chunk)

    int n1 = nc * 7;

    // ---- issue row-0 loads first (longest latency) ----
    float4 pa = *reinterpret_cast<const float4*>(xbase + ja * 784 + n1 * 28 + ma * 4);
    float4 pb = make_float4(0.f, 0.f, 0.f, 0.f);
    if (vb) pb = *reinterpret_cast<const float4*>(xbase + jb2 * 784 + n1 * 28 + mb * 4);

    // ---- W fragments: bw[s][e] = W[jb+e][kw][ig], K = kw*128 + j ----
    const int ig = wave * 16 + l15;
    bf16x8 bw[12];
#pragma unroll
    for (int s = 0; s < 12; ++s) {
        const int kw = s >> 2;
        const int jb = (s & 3) * 32 + hi2 * 8;
#pragma unroll
        for (int e = 0; e < 8; ++e)
            bw[s][e] = (__bf16)Wm[((jb + e) * 3 + kw) * 128 + ig];
    }

    // ---- zero pad rows 0 and 29 of both buffers (never overwritten) ----
    {
        const int buf = tid >> 8;                 // 0,1
        const int r   = ((tid >> 7) & 1) ? 29 : 0;
        const int j   = tid & 127;
        xsp[buf][swz(r, j)] = 0;
    }

    // ---- write row 0 into buf 0 ----
    STAGE_WRITE(0, pa, ja, ma);
    if (vb) STAGE_WRITE(0, pb, jb2, mb);

    int cur = 0;
#pragma unroll 1
    for (int t = 0; t < 7; ++t) {
        __syncthreads();   // buf[cur] writes visible; prior reads drained

        // prefetch row t+1 (issued before compute so HBM latency overlaps)
        float4 na, nb;
        const bool more = (t < 6);
        if (more) {
            na = *reinterpret_cast<const float4*>(xbase + ja * 784 + (n1 + 1) * 28 + ma * 4);
            if (vb) nb = *reinterpret_cast<const float4*>(xbase + jb2 * 784 + (n1 + 1) * 28 + mb * 4);
        }

        // ---- 24 MFMA from buf[cur] ----
        f32x4 acc0 = {0.f, 0.f, 0.f, 0.f};
        f32x4 acc1 = {0.f, 0.f, 0.f, 0.f};
        const unsigned short* xs = xsp[cur];
#pragma unroll
        for (int s = 0; s < 12; ++s) {
            const int kw = s >> 2;
            const int jb = (s & 3) * 32 + hi2 * 8;
            const bf16x8 a0 = *reinterpret_cast<const bf16x8*>(&xs[swz(l15 + kw, jb)]);
            acc0 = __builtin_amdgcn_mfma_f32_16x16x32_bf16(a0, bw[s], acc0, 0, 0, 0);
            const bf16x8 a1 = *reinterpret_cast<const bf16x8*>(&xs[swz(16 + l15 + kw, jb)]);
            acc1 = __builtin_amdgcn_mfma_f32_16x16x32_bf16(a1, bw[s], acc1, 0, 0, 0);
        }

        // ---- store: C row m = mt*16 + hi2*4 + reg, col i = ig ----
        const int n = (n1 + 1) % 28;
        float* op = obase + (size_t)ig * 784 + n * 28;
        *reinterpret_cast<float4*>(op + hi2 * 4) =
            make_float4(acc0[0], acc0[1], acc0[2], acc0[3]);
        if (hi2 < 3)
            *reinterpret_cast<float4*>(op + 16 + hi2 * 4) =
                make_float4(acc1[0], acc1[1], acc1[2], acc1[3]);

        // ---- convert + write row t+1 into buf^1 (loads have had MFMA to land) ----
        if (more) {
            STAGE_WRITE(cur ^ 1, na, ja, ma);
            if (vb) STAGE_WRITE(cur ^ 1, nb, jb2, mb);
        }
        cur ^= 1;
        ++n1;
    }
}

extern "C" void kernel_launch(void* const* d_in, const int* in_sizes, int n_in,
                              void* d_out, int out_size, void* d_ws, size_t ws_size,
                              hipStream_t stream) {
    const float* x  = (const float*)d_in[0];   // (128, 256, 28, 28) fp32
    const float* Wm = (const float*)d_in[1];   // (128, 3, 128) fp32
    float* out = (float*)d_out;                // (128, 256, 28, 28) fp32
    hipLaunchKernelGGL(shiftconv_kernel, dim3(1024), dim3(512), 0, stream, x, Wm, out);
}